// Round 5
// baseline (491.904 us; speedup 1.0000x reference)
//
#include <hip/hip_runtime.h>

#define NB   2048
#define SEQ  200
#define DIM  64
#define NH1  64
#define NH2  16
#define EPSF 1e-9f
#define ROWS1 4          // batch rows per prep block

typedef float fvec4 __attribute__((ext_vector_type(4)));
typedef short svec8 __attribute__((ext_vector_type(8)));   // 8 bf16 = 4 VGPRs

__device__ __forceinline__ short f2bf(float f) {
    unsigned u = __float_as_uint(f);
    u += 0x7fffu + ((u >> 16) & 1u);      // round-to-nearest-even
    return (short)(u >> 16);
}

// ---------------- kernel 1: fold q into W1, emit bf16 B-frags + qterm ----------------
__global__ __launch_bounds__(256, 2)
void din_prep_kernel(const float* __restrict__ q,     // [B,64]
                     const float* __restrict__ W1,    // [256,64]
                     char*  __restrict__ wsA,
                     float* __restrict__ qtermws)
{
    __shared__ float Wsub[4096];   // W1b - W1c
    __shared__ float Wd[4096];     // W1d
    __shared__ float Wac[4096];    // W1a + W1c
    const int t = threadIdx.x;

    #pragma unroll
    for (int it = 0; it < 16; ++it) {
        const int e = it * 256 + t;            // 4096 (d,h) pairs
        const int d = e >> 6, h = e & 63;
        const float w1a = W1[d * 64 + h];
        const float w1b = W1[(64 + d) * 64 + h];
        const float w1c = W1[(128 + d) * 64 + h];
        const float w1dv= W1[(192 + d) * 64 + h];
        Wsub[e] = w1b - w1c;
        Wac[e]  = w1a + w1c;
        Wd[e]   = w1dv;
    }
    __syncthreads();

    const int lane = t & 63;
    const int wave = t >> 6;        // doubles as column block c and h-block
    const int qd4  = lane >> 4;
    const int m    = lane & 15;

    for (int r = 0; r < ROWS1; ++r) {
        const int b = blockIdx.x * ROWS1 + r;
        const float* qrow = q + (size_t)b * DIM;

        // qterm[h = wave*16 + m], in-wave reduce over qd4 blocks of d
        {
            const int h = wave * 16 + m;
            float s = 0.f;
            #pragma unroll
            for (int i = 0; i < 16; ++i) {
                const int d = qd4 * 16 + i;
                s = fmaf(qrow[d], Wac[d * 64 + h], s);
            }
            s += __shfl_xor(s, 16);
            s += __shfl_xor(s, 32);
            if (qd4 == 0) qtermws[(size_t)b * 64 + h] = s;
        }

        // B-frags for column block c = wave
        #pragma unroll
        for (int kk = 0; kk < 2; ++kk) {
            svec8 f;
            #pragma unroll
            for (int j = 0; j < 8; ++j) {
                const int d = kk * 32 + qd4 * 8 + j;
                const int h = wave * 16 + m;
                f[j] = f2bf(Wsub[d * 64 + h] + qrow[d] * Wd[d * 64 + h]);
            }
            *(svec8*)(wsA + (size_t)b * 8192 + (((wave << 1) + kk) << 10) + lane * 16) = f;
        }
    }
}

// ---------------- kernel 2: one wave per batch row, zero barriers ----------------
__global__ __launch_bounds__(64, 2)
void din_main_kernel(const float* __restrict__ key,     // [B,200,64]
                     const int*   __restrict__ seqlen,  // [B,1]
                     const float* __restrict__ W2,      // [64,16]
                     const float* __restrict__ alpha1v,
                     const float* __restrict__ mean1v,
                     const float* __restrict__ var1v,
                     const float* __restrict__ alpha2v,
                     const float* __restrict__ mean2v,
                     const float* __restrict__ var2v,
                     const float* __restrict__ W3,      // [16]
                     const char*  __restrict__ wsA,
                     const float* __restrict__ qtermws,
                     float* __restrict__ out)           // [B,64]
{
    __shared__ short h1w[16 * NH1];   // 2 KB, single wave
    __shared__ float wsw[16];

    const int b    = blockIdx.x;
    const int lane = threadIdx.x;     // 0..63
    const int qd4  = lane >> 4;
    const int m    = lane & 15;

    int nseq = seqlen[b];
    nseq = nseq < SEQ ? nseq : SEQ;

    // ---- prologue: everything pre-packed
    svec8 wcf[4][2];
    {
        const char* fb = wsA + (size_t)b * 8192 + (size_t)lane * 16;
        #pragma unroll
        for (int c = 0; c < 4; ++c)
            #pragma unroll
            for (int kk = 0; kk < 2; ++kk)
                wcf[c][kk] = *(const svec8*)(fb + (((c << 1) + kk) << 10));
    }
    float qtermv[4];
    #pragma unroll
    for (int c = 0; c < 4; ++c) qtermv[c] = qtermws[(size_t)b * 64 + c * 16 + m];

    svec8 w2f[2];
    #pragma unroll
    for (int kk = 0; kk < 2; ++kk) {
        svec8 f;
        #pragma unroll
        for (int j = 0; j < 8; ++j)
            f[j] = f2bf(W2[(kk * 32 + qd4 * 8 + j) * NH2 + m]);
        w2f[kk] = f;
    }

    float a1v[4], m1v[4], r1v[4];
    #pragma unroll
    for (int c = 0; c < 4; ++c) {
        a1v[c] = alpha1v[c * 16 + m];
        m1v[c] = mean1v[c * 16 + m];
        r1v[c] = rsqrtf(var1v[c * 16 + m] + EPSF);
    }
    const float a2s = alpha2v[m];
    const float m2s = mean2v[m];
    const float r2s = rsqrtf(var2v[m] + EPSF);
    const float w3s = W3[m];

    fvec4 oacc0 = {0.f,0.f,0.f,0.f}, oacc1 = {0.f,0.f,0.f,0.f};
    fvec4 oacc2 = {0.f,0.f,0.f,0.f}, oacc3 = {0.f,0.f,0.f,0.f};

    const int ntiles = (nseq + 15) >> 4;
    const float* kbase = key + (size_t)b * SEQ * DIM + qd4 * 8;

    // 1-deep software prefetch of the k tile (A-frag layout direct from global)
    fvec4 nv0, nv1, nv2, nv3;
    {
        const float* kp = kbase + (size_t)m * DIM;      // tile 0, row m
        nv0 = *(const fvec4*)(kp);
        nv1 = *(const fvec4*)(kp + 4);
        nv2 = *(const fvec4*)(kp + 32);
        nv3 = *(const fvec4*)(kp + 36);
    }

    for (int tile = 0; tile < ntiles; ++tile) {
        const fvec4 kv0 = nv0, kv1 = nv1, kv2 = nv2, kv3 = nv3;
        if (tile + 1 < ntiles) {
            int row = (tile + 1) * 16 + m;
            row = row < SEQ ? row : SEQ - 1;            // clamp; masked by w=0
            const float* kp = kbase + (size_t)row * DIM;
            nv0 = *(const fvec4*)(kp);
            nv1 = *(const fvec4*)(kp + 4);
            nv2 = *(const fvec4*)(kp + 32);
            nv3 = *(const fvec4*)(kp + 36);
        }

        svec8 af0, af1;
        #pragma unroll
        for (int j = 0; j < 4; ++j) {
            af0[j]     = f2bf(kv0[j]);
            af0[4 + j] = f2bf(kv1[j]);
            af1[j]     = f2bf(kv2[j]);
            af1[4 + j] = f2bf(kv3[j]);
        }

        // phase 1: x[16][64] = k @ Wc ; dice1 ; h1 -> LDS row-major [row][h]
        #pragma unroll
        for (int c = 0; c < 4; ++c) {
            fvec4 acc = (fvec4){0.f, 0.f, 0.f, 0.f};
            acc = __builtin_amdgcn_mfma_f32_16x16x32_bf16(af0, wcf[c][0], acc, 0, 0, 0);
            acc = __builtin_amdgcn_mfma_f32_16x16x32_bf16(af1, wcf[c][1], acc, 0, 0, 0);
            #pragma unroll
            for (int reg = 0; reg < 4; ++reg) {
                const float x  = acc[reg] + qtermv[c];
                const float xn = (x - m1v[c]) * r1v[c];
                const float p  = 1.f / (1.f + __expf(-xn));
                const float h1 = x * (a1v[c] + p * (1.f - a1v[c]));
                h1w[(qd4 * 4 + reg) * NH1 + c * 16 + m] = f2bf(h1);
            }
        }
        // same-wave LDS write->read (in-order DS pipe; validated r2/r3)

        // phase 2: h2 = h1 @ W2 ; dice2 ; score ; weights
        const svec8 b0 = *(const svec8*)(h1w + m * NH1 + qd4 * 8);
        const svec8 b1 = *(const svec8*)(h1w + m * NH1 + 32 + qd4 * 8);
        fvec4 acc2 = (fvec4){0.f, 0.f, 0.f, 0.f};
        acc2 = __builtin_amdgcn_mfma_f32_16x16x32_bf16(b0, w2f[0], acc2, 0, 0, 0);
        acc2 = __builtin_amdgcn_mfma_f32_16x16x32_bf16(b1, w2f[1], acc2, 0, 0, 0);

        #pragma unroll
        for (int reg = 0; reg < 4; ++reg) {
            const float x  = acc2[reg];                 // h2[qd4*4+reg][j=m]
            const float xn = (x - m2s) * r2s;
            const float p  = 1.f / (1.f + __expf(-xn));
            const float hd = x * (a2s + p * (1.f - a2s));
            float s = hd * w3s;
            s += __shfl_xor(s, 1);
            s += __shfl_xor(s, 2);
            s += __shfl_xor(s, 4);
            s += __shfl_xor(s, 8);                      // sum over 16 j-lanes
            if (m == 0) {
                const int rg = tile * 16 + qd4 * 4 + reg;
                wsw[qd4 * 4 + reg] = (rg < nseq) ? 1.f / (1.f + __expf(-s)) : 0.f;
            }
        }

        // phase 3: weighted sum from the fp32 regs already in hand
        const float w = wsw[m];
        oacc0 += w * kv0;
        oacc1 += w * kv1;
        oacc2 += w * kv2;
        oacc3 += w * kv3;
    }

    // ---- reduce over the 16 m-lanes (rows), store directly
    #pragma unroll
    for (int e = 0; e < 4; ++e) {
        float v0 = oacc0[e], v1 = oacc1[e], v2 = oacc2[e], v3 = oacc3[e];
        #pragma unroll
        for (int msk = 1; msk < 16; msk <<= 1) {
            v0 += __shfl_xor(v0, msk);
            v1 += __shfl_xor(v1, msk);
            v2 += __shfl_xor(v2, msk);
            v3 += __shfl_xor(v3, msk);
        }
        oacc0[e] = v0; oacc1[e] = v1; oacc2[e] = v2; oacc3[e] = v3;
    }
    if (m == 0) {
        float* op = out + (size_t)b * DIM + qd4 * 8;
        *(fvec4*)(op)      = oacc0;
        *(fvec4*)(op + 4)  = oacc1;
        *(fvec4*)(op + 32) = oacc2;
        *(fvec4*)(op + 36) = oacc3;
    }
}

extern "C" void kernel_launch(void* const* d_in, const int* in_sizes, int n_in,
                              void* d_out, int out_size, void* d_ws, size_t ws_size,
                              hipStream_t stream) {
    const float* q      = (const float*)d_in[0];
    const float* key    = (const float*)d_in[1];
    const int*   seqlen = (const int*)d_in[2];
    const float* W1     = (const float*)d_in[3];
    const float* alpha1 = (const float*)d_in[4];
    const float* mean1  = (const float*)d_in[5];
    const float* var1   = (const float*)d_in[6];
    const float* W2     = (const float*)d_in[7];
    const float* alpha2 = (const float*)d_in[8];
    const float* mean2  = (const float*)d_in[9];
    const float* var2   = (const float*)d_in[10];
    const float* W3     = (const float*)d_in[11];
    float* out          = (float*)d_out;

    char*  wsA     = (char*)d_ws;                               // 2048 * 8192 B
    float* qtermws = (float*)((char*)d_ws + (size_t)NB * 8192); // + 512 KB

    din_prep_kernel<<<NB / ROWS1, 256, 0, stream>>>(q, W1, wsA, qtermws);

    // ATTRIBUTION EXPERIMENT: launch the (idempotent) main kernel 9x.
    // dur_us slope vs round-4 single-launch directly measures per-launch cost.
    for (int rep = 0; rep < 9; ++rep) {
        din_main_kernel<<<NB, 64, 0, stream>>>(key, seqlen, W2,
                                               alpha1, mean1, var1,
                                               alpha2, mean2, var2,
                                               W3, wsA, qtermws, out);
    }
}

// Round 6
// 198.078 us; speedup vs baseline: 2.4834x; 2.4834x over previous
//
#include <hip/hip_runtime.h>

#define NB   2048
#define SEQ  200
#define DIM  64
#define NH1  64
#define NH2  16
#define EPSF 1e-9f
#define ROWS1 4          // batch rows per prep block

typedef float fvec4 __attribute__((ext_vector_type(4)));
typedef short svec8 __attribute__((ext_vector_type(8)));   // 8 bf16 = 4 VGPRs

__device__ __forceinline__ short f2bf(float f) {
    unsigned u = __float_as_uint(f);
    u += 0x7fffu + ((u >> 16) & 1u);      // round-to-nearest-even
    return (short)(u >> 16);
}

// ---------------- kernel 1: fold q into W1, emit bf16 B-frags + qterm ----------------
__global__ __launch_bounds__(256, 2)
void din_prep_kernel(const float* __restrict__ q,     // [B,64]
                     const float* __restrict__ W1,    // [256,64]
                     char*  __restrict__ wsA,
                     float* __restrict__ qtermws)
{
    __shared__ float Wsub[4096];   // W1b - W1c
    __shared__ float Wd[4096];     // W1d
    __shared__ float Wac[4096];    // W1a + W1c
    const int t = threadIdx.x;

    #pragma unroll
    for (int it = 0; it < 16; ++it) {
        const int e = it * 256 + t;            // 4096 (d,h) pairs
        const int d = e >> 6, h = e & 63;
        const float w1a = W1[d * 64 + h];
        const float w1b = W1[(64 + d) * 64 + h];
        const float w1c = W1[(128 + d) * 64 + h];
        const float w1dv= W1[(192 + d) * 64 + h];
        Wsub[e] = w1b - w1c;
        Wac[e]  = w1a + w1c;
        Wd[e]   = w1dv;
    }
    __syncthreads();

    const int lane = t & 63;
    const int wave = t >> 6;        // doubles as column block c and h-block
    const int qd4  = lane >> 4;
    const int m    = lane & 15;

    for (int r = 0; r < ROWS1; ++r) {
        const int b = blockIdx.x * ROWS1 + r;
        const float* qrow = q + (size_t)b * DIM;

        // qterm[h = wave*16 + m], in-wave reduce over qd4 blocks of d
        {
            const int h = wave * 16 + m;
            float s = 0.f;
            #pragma unroll
            for (int i = 0; i < 16; ++i) {
                const int d = qd4 * 16 + i;
                s = fmaf(qrow[d], Wac[d * 64 + h], s);
            }
            s += __shfl_xor(s, 16);
            s += __shfl_xor(s, 32);
            if (qd4 == 0) qtermws[(size_t)b * 64 + h] = s;
        }

        // B-frags for column block c = wave
        #pragma unroll
        for (int kk = 0; kk < 2; ++kk) {
            svec8 f;
            #pragma unroll
            for (int j = 0; j < 8; ++j) {
                const int d = kk * 32 + qd4 * 8 + j;
                const int h = wave * 16 + m;
                f[j] = f2bf(Wsub[d * 64 + h] + qrow[d] * Wd[d * 64 + h]);
            }
            *(svec8*)(wsA + (size_t)b * 8192 + (((wave << 1) + kk) << 10) + lane * 16) = f;
        }
    }
}

// ---------------- kernel 2: two waves per batch row (tile parity), no wsw LDS ----------------
__global__ __launch_bounds__(128, 4)
void din_main_kernel(const float* __restrict__ key,     // [B,200,64]
                     const int*   __restrict__ seqlen,  // [B,1]
                     const float* __restrict__ W2,      // [64,16]
                     const float* __restrict__ alpha1v,
                     const float* __restrict__ mean1v,
                     const float* __restrict__ var1v,
                     const float* __restrict__ alpha2v,
                     const float* __restrict__ mean2v,
                     const float* __restrict__ var2v,
                     const float* __restrict__ W3,      // [16]
                     const char*  __restrict__ wsA,
                     const float* __restrict__ qtermws,
                     float* __restrict__ out)           // [B,64]
{
    __shared__ short h1base[2][16 * NH1];   // 4 KB, per-wave
    __shared__ float obuf[2 * 64];

    const int b    = blockIdx.x;
    const int t    = threadIdx.x;           // 0..127
    const int lane = t & 63;
    const int wave = __builtin_amdgcn_readfirstlane(t >> 6);
    const int qd4  = lane >> 4;
    const int m    = lane & 15;

    short* h1w = h1base[wave];

    int nseq = seqlen[b];
    nseq = nseq < SEQ ? nseq : SEQ;

    // ---- prologue: everything pre-packed
    svec8 wcf[4][2];
    {
        const char* fb = wsA + (size_t)b * 8192 + (size_t)lane * 16;
        #pragma unroll
        for (int c = 0; c < 4; ++c)
            #pragma unroll
            for (int kk = 0; kk < 2; ++kk)
                wcf[c][kk] = *(const svec8*)(fb + (((c << 1) + kk) << 10));
    }
    float qtermv[4];
    #pragma unroll
    for (int c = 0; c < 4; ++c) qtermv[c] = qtermws[(size_t)b * 64 + c * 16 + m];

    svec8 w2f[2];
    #pragma unroll
    for (int kk = 0; kk < 2; ++kk) {
        svec8 f;
        #pragma unroll
        for (int j = 0; j < 8; ++j)
            f[j] = f2bf(W2[(kk * 32 + qd4 * 8 + j) * NH2 + m]);
        w2f[kk] = f;
    }

    float a1v[4], m1v[4], r1v[4];
    #pragma unroll
    for (int c = 0; c < 4; ++c) {
        a1v[c] = alpha1v[c * 16 + m];
        m1v[c] = mean1v[c * 16 + m];
        r1v[c] = rsqrtf(var1v[c * 16 + m] + EPSF);
    }
    const float a2s = alpha2v[m];
    const float m2s = mean2v[m];
    const float r2s = rsqrtf(var2v[m] + EPSF);
    const float w3s = W3[m];

    fvec4 oacc0 = {0.f,0.f,0.f,0.f}, oacc1 = {0.f,0.f,0.f,0.f};
    fvec4 oacc2 = {0.f,0.f,0.f,0.f}, oacc3 = {0.f,0.f,0.f,0.f};

    const int ntiles = (nseq + 15) >> 4;
    const float* kbase = key + (size_t)b * SEQ * DIM + qd4 * 8;

    for (int tile = wave; tile < ntiles; tile += 2) {
        int row = tile * 16 + m;
        row = row < SEQ ? row : SEQ - 1;             // clamp; masked by w=0
        const float* kp = kbase + (size_t)row * DIM;
        const fvec4 kv0 = *(const fvec4*)(kp);
        const fvec4 kv1 = *(const fvec4*)(kp + 4);
        const fvec4 kv2 = *(const fvec4*)(kp + 32);
        const fvec4 kv3 = *(const fvec4*)(kp + 36);

        svec8 af0, af1;
        #pragma unroll
        for (int j = 0; j < 4; ++j) {
            af0[j]     = f2bf(kv0[j]);
            af0[4 + j] = f2bf(kv1[j]);
            af1[j]     = f2bf(kv2[j]);
            af1[4 + j] = f2bf(kv3[j]);
        }

        // phase 1: x[16][64] = k @ Wc (+qterm via C-init) ; dice1 ; h1 -> LDS
        #pragma unroll
        for (int c = 0; c < 4; ++c) {
            const float qt = qtermv[c];
            fvec4 acc = (fvec4){qt, qt, qt, qt};     // qterm depends on h only
            acc = __builtin_amdgcn_mfma_f32_16x16x32_bf16(af0, wcf[c][0], acc, 0, 0, 0);
            acc = __builtin_amdgcn_mfma_f32_16x16x32_bf16(af1, wcf[c][1], acc, 0, 0, 0);
            #pragma unroll
            for (int reg = 0; reg < 4; ++reg) {
                const float x  = acc[reg];
                const float xn = (x - m1v[c]) * r1v[c];
                const float p  = 1.f / (1.f + __expf(-xn));
                const float h1 = x * (a1v[c] + p * (1.f - a1v[c]));
                h1w[(qd4 * 4 + reg) * NH1 + c * 16 + m] = f2bf(h1);
            }
        }
        // same-wave LDS write->read (in-order DS pipe; validated r2-r5)

        // phase 2: h2 = h1 @ W2 ; dice2 ; score partials
        const svec8 b0 = *(const svec8*)(h1w + m * NH1 + qd4 * 8);
        const svec8 b1 = *(const svec8*)(h1w + m * NH1 + 32 + qd4 * 8);
        fvec4 acc2 = (fvec4){0.f, 0.f, 0.f, 0.f};
        acc2 = __builtin_amdgcn_mfma_f32_16x16x32_bf16(b0, w2f[0], acc2, 0, 0, 0);
        acc2 = __builtin_amdgcn_mfma_f32_16x16x32_bf16(b1, w2f[1], acc2, 0, 0, 0);

        float sreg[4];
        #pragma unroll
        for (int reg = 0; reg < 4; ++reg) {
            const float x  = acc2[reg];              // h2[qd4*4+reg][j=m]
            const float xn = (x - m2s) * r2s;
            const float p  = 1.f / (1.f + __expf(-xn));
            const float hd = x * (a2s + p * (1.f - a2s));
            sreg[reg] = hd * w3s;
        }
        // reduce over the 16 j-lanes of each group (independent chains x4)
        #pragma unroll
        for (int msk = 1; msk < 16; msk <<= 1) {
            sreg[0] += __shfl_xor(sreg[0], msk);
            sreg[1] += __shfl_xor(sreg[1], msk);
            sreg[2] += __shfl_xor(sreg[2], msk);
            sreg[3] += __shfl_xor(sreg[3], msk);
        }
        // broadcast: lane needs score of row m, held by group (m>>2), reg (m&3)
        const int src = (m >> 2) << 4;               // one parallel shfl layer
        const float s0b = __shfl(sreg[0], src);
        const float s1b = __shfl(sreg[1], src);
        const float s2b = __shfl(sreg[2], src);
        const float s3b = __shfl(sreg[3], src);
        const float sa = (m & 1) ? s1b : s0b;
        const float sb = (m & 1) ? s3b : s2b;
        const float sv = (m & 2) ? sb : sa;

        const int   rg = tile * 16 + m;
        const float pw = 1.f / (1.f + __expf(-sv));
        const float w  = (rg < nseq) ? pw : 0.f;

        // phase 3: weighted sum from the fp32 regs already in hand
        oacc0 += w * kv0;
        oacc1 += w * kv1;
        oacc2 += w * kv2;
        oacc3 += w * kv3;
    }

    // ---- reduce over the 16 m-lanes (rows) within each wave
    #pragma unroll
    for (int e = 0; e < 4; ++e) {
        float v0 = oacc0[e], v1 = oacc1[e], v2 = oacc2[e], v3 = oacc3[e];
        #pragma unroll
        for (int msk = 1; msk < 16; msk <<= 1) {
            v0 += __shfl_xor(v0, msk);
            v1 += __shfl_xor(v1, msk);
            v2 += __shfl_xor(v2, msk);
            v3 += __shfl_xor(v3, msk);
        }
        oacc0[e] = v0; oacc1[e] = v1; oacc2[e] = v2; oacc3[e] = v3;
    }
    if (m == 0) {
        float* op = obuf + wave * 64 + qd4 * 8;
        *(fvec4*)(op)      = oacc0;
        *(fvec4*)(op + 4)  = oacc1;
        *(fvec4*)(op + 32) = oacc2;
        *(fvec4*)(op + 36) = oacc3;
    }
    __syncthreads();
    if (t < 64)
        out[(size_t)b * DIM + t] = obuf[t] + obuf[64 + t];
}

extern "C" void kernel_launch(void* const* d_in, const int* in_sizes, int n_in,
                              void* d_out, int out_size, void* d_ws, size_t ws_size,
                              hipStream_t stream) {
    const float* q      = (const float*)d_in[0];
    const float* key    = (const float*)d_in[1];
    const int*   seqlen = (const int*)d_in[2];
    const float* W1     = (const float*)d_in[3];
    const float* alpha1 = (const float*)d_in[4];
    const float* mean1  = (const float*)d_in[5];
    const float* var1   = (const float*)d_in[6];
    const float* W2     = (const float*)d_in[7];
    const float* alpha2 = (const float*)d_in[8];
    const float* mean2  = (const float*)d_in[9];
    const float* var2   = (const float*)d_in[10];
    const float* W3     = (const float*)d_in[11];
    float* out          = (float*)d_out;

    char*  wsA     = (char*)d_ws;                               // 2048 * 8192 B
    float* qtermws = (float*)((char*)d_ws + (size_t)NB * 8192); // + 512 KB

    din_prep_kernel<<<NB / ROWS1, 256, 0, stream>>>(q, W1, wsA, qtermws);
    din_main_kernel<<<NB, 128, 0, stream>>>(key, seqlen, W2,
                                            alpha1, mean1, var1,
                                            alpha2, mean2, var2,
                                            W3, wsA, qtermws, out);
}

// Round 7
// 190.091 us; speedup vs baseline: 2.5877x; 1.0420x over previous
//
#include <hip/hip_runtime.h>

#define NB   2048
#define SEQ  200
#define DIM  64
#define NH1  64
#define NH2  16
#define EPSF 1e-9f

typedef float fvec4 __attribute__((ext_vector_type(4)));
typedef short svec8 __attribute__((ext_vector_type(8)));   // 8 bf16 = 4 VGPRs

__device__ __forceinline__ short f2bf(float f) {
    unsigned u = __float_as_uint(f);
    u += 0x7fffu + ((u >> 16) & 1u);      // round-to-nearest-even
    return (short)(u >> 16);
}

// Single fused kernel: 2 waves per batch row. Evidence (r2..r6): dur_us tracks
// launch count, not main-loop structure -> minimize launches (1) and keep the
// best-measured main loop (r6). Setup stages q-folded Wc as bf16 in LDS once
// per block (one barrier), then each wave streams its parity of k-tiles
// end-to-end in registers.
__global__ __launch_bounds__(128, 4)
void din_attn_kernel(const float* __restrict__ q,        // [B,64]
                     const float* __restrict__ key,      // [B,200,64]
                     const int*   __restrict__ seqlen,   // [B,1]
                     const float* __restrict__ W1,       // [256,64]
                     const float* __restrict__ alpha1v,
                     const float* __restrict__ mean1v,
                     const float* __restrict__ var1v,
                     const float* __restrict__ W2,       // [64,16]
                     const float* __restrict__ alpha2v,
                     const float* __restrict__ mean2v,
                     const float* __restrict__ var2v,
                     const float* __restrict__ W3,       // [16]
                     float* __restrict__ out)            // [B,64]
{
    __shared__ short wc_bf[DIM * NH1];      // 8 KB: Wc[d][h] bf16
    __shared__ float qpart[2][NH1];         // 512 B
    __shared__ short h1base[2][16 * NH1];   // 4 KB: per-wave h1 tiles
    __shared__ float obuf[2 * 64];          // 512 B

    const int b    = blockIdx.x;
    const int t    = threadIdx.x;           // 0..127
    const int lane = t & 63;
    const int wave = __builtin_amdgcn_readfirstlane(t >> 6);
    const int qd4  = lane >> 4;
    const int m    = lane & 15;

    short* h1w = h1base[wave];

    const float* qrow = q + (size_t)b * DIM;
    int nseq = seqlen[b];
    nseq = nseq < SEQ ? nseq : SEQ;

    // ---- setup: Wc[d][h] = (W1b - W1c) + q[d]*W1d  (bf16 -> LDS);
    //             qterm[h] = sum_d q[d]*(W1a + W1c)[d][h]  (partials -> LDS)
    {
        const int h = lane;                  // coalesced over h
        float qt = 0.f;
        #pragma unroll
        for (int i = 0; i < 32; ++i) {
            const int d = wave * 32 + i;     // wave-uniform
            const float qd  = qrow[d];       // -> sgpr
            const float w1a = W1[(d)       * NH1 + h];
            const float w1b = W1[(64 + d)  * NH1 + h];
            const float w1c = W1[(128 + d) * NH1 + h];
            const float w1dd= W1[(192 + d) * NH1 + h];
            wc_bf[d * NH1 + h] = f2bf((w1b - w1c) + qd * w1dd);
            qt = fmaf(qd, w1a + w1c, qt);
        }
        qpart[wave][h] = qt;
    }
    __syncthreads();

    // ---- gather B-frags from LDS (2-way conflicts only -> free); params
    float qtermv[4];
    #pragma unroll
    for (int c = 0; c < 4; ++c)
        qtermv[c] = qpart[0][c * 16 + m] + qpart[1][c * 16 + m];

    svec8 wcf[4][2];
    #pragma unroll
    for (int c = 0; c < 4; ++c)
        #pragma unroll
        for (int kk = 0; kk < 2; ++kk) {
            svec8 f;
            #pragma unroll
            for (int j = 0; j < 8; ++j)
                f[j] = wc_bf[(kk * 32 + qd4 * 8 + j) * NH1 + c * 16 + m];
            wcf[c][kk] = f;
        }

    svec8 w2f[2];
    #pragma unroll
    for (int kk = 0; kk < 2; ++kk) {
        svec8 f;
        #pragma unroll
        for (int j = 0; j < 8; ++j)
            f[j] = f2bf(W2[(kk * 32 + qd4 * 8 + j) * NH2 + m]);
        w2f[kk] = f;
    }

    float a1v[4], m1v[4], r1v[4];
    #pragma unroll
    for (int c = 0; c < 4; ++c) {
        a1v[c] = alpha1v[c * 16 + m];
        m1v[c] = mean1v[c * 16 + m];
        r1v[c] = rsqrtf(var1v[c * 16 + m] + EPSF);
    }
    const float a2s = alpha2v[m];
    const float m2s = mean2v[m];
    const float r2s = rsqrtf(var2v[m] + EPSF);
    const float w3s = W3[m];

    fvec4 oacc0 = {0.f,0.f,0.f,0.f}, oacc1 = {0.f,0.f,0.f,0.f};
    fvec4 oacc2 = {0.f,0.f,0.f,0.f}, oacc3 = {0.f,0.f,0.f,0.f};

    const int ntiles = (nseq + 15) >> 4;
    const float* kbase = key + (size_t)b * SEQ * DIM + qd4 * 8;

    for (int tile = wave; tile < ntiles; tile += 2) {
        int row = tile * 16 + m;
        row = row < SEQ ? row : SEQ - 1;             // clamp; masked by w=0
        const float* kp = kbase + (size_t)row * DIM;
        const fvec4 kv0 = *(const fvec4*)(kp);
        const fvec4 kv1 = *(const fvec4*)(kp + 4);
        const fvec4 kv2 = *(const fvec4*)(kp + 32);
        const fvec4 kv3 = *(const fvec4*)(kp + 36);

        svec8 af0, af1;
        #pragma unroll
        for (int j = 0; j < 4; ++j) {
            af0[j]     = f2bf(kv0[j]);
            af0[4 + j] = f2bf(kv1[j]);
            af1[j]     = f2bf(kv2[j]);
            af1[4 + j] = f2bf(kv3[j]);
        }

        // phase 1: x[16][64] = k @ Wc (+qterm via C-init) ; dice1 ; h1 -> LDS
        #pragma unroll
        for (int c = 0; c < 4; ++c) {
            const float qt = qtermv[c];
            fvec4 acc = (fvec4){qt, qt, qt, qt};     // qterm depends on h only
            acc = __builtin_amdgcn_mfma_f32_16x16x32_bf16(af0, wcf[c][0], acc, 0, 0, 0);
            acc = __builtin_amdgcn_mfma_f32_16x16x32_bf16(af1, wcf[c][1], acc, 0, 0, 0);
            #pragma unroll
            for (int reg = 0; reg < 4; ++reg) {
                const float x  = acc[reg];
                const float xn = (x - m1v[c]) * r1v[c];
                const float p  = 1.f / (1.f + __expf(-xn));
                const float h1 = x * (a1v[c] + p * (1.f - a1v[c]));
                h1w[(qd4 * 4 + reg) * NH1 + c * 16 + m] = f2bf(h1);
            }
        }
        // same-wave LDS write->read (in-order DS pipe; validated r2-r6)

        // phase 2: h2 = h1 @ W2 ; dice2 ; score partials
        const svec8 b0 = *(const svec8*)(h1w + m * NH1 + qd4 * 8);
        const svec8 b1 = *(const svec8*)(h1w + m * NH1 + 32 + qd4 * 8);
        fvec4 acc2 = (fvec4){0.f, 0.f, 0.f, 0.f};
        acc2 = __builtin_amdgcn_mfma_f32_16x16x32_bf16(b0, w2f[0], acc2, 0, 0, 0);
        acc2 = __builtin_amdgcn_mfma_f32_16x16x32_bf16(b1, w2f[1], acc2, 0, 0, 0);

        float sreg[4];
        #pragma unroll
        for (int reg = 0; reg < 4; ++reg) {
            const float x  = acc2[reg];              // h2[qd4*4+reg][j=m]
            const float xn = (x - m2s) * r2s;
            const float p  = 1.f / (1.f + __expf(-xn));
            const float hd = x * (a2s + p * (1.f - a2s));
            sreg[reg] = hd * w3s;
        }
        #pragma unroll
        for (int msk = 1; msk < 16; msk <<= 1) {
            sreg[0] += __shfl_xor(sreg[0], msk);
            sreg[1] += __shfl_xor(sreg[1], msk);
            sreg[2] += __shfl_xor(sreg[2], msk);
            sreg[3] += __shfl_xor(sreg[3], msk);
        }
        // broadcast: lane needs score of row m, held by group (m>>2), reg (m&3)
        const int src = (m >> 2) << 4;
        const float s0b = __shfl(sreg[0], src);
        const float s1b = __shfl(sreg[1], src);
        const float s2b = __shfl(sreg[2], src);
        const float s3b = __shfl(sreg[3], src);
        const float sa = (m & 1) ? s1b : s0b;
        const float sb = (m & 1) ? s3b : s2b;
        const float sv = (m & 2) ? sb : sa;

        const int   rg = tile * 16 + m;
        const float pw = 1.f / (1.f + __expf(-sv));
        const float w  = (rg < nseq) ? pw : 0.f;

        // phase 3: weighted sum from the fp32 regs already in hand
        oacc0 += w * kv0;
        oacc1 += w * kv1;
        oacc2 += w * kv2;
        oacc3 += w * kv3;
    }

    // ---- reduce over the 16 m-lanes (rows) within each wave
    #pragma unroll
    for (int e = 0; e < 4; ++e) {
        float v0 = oacc0[e], v1 = oacc1[e], v2 = oacc2[e], v3 = oacc3[e];
        #pragma unroll
        for (int msk = 1; msk < 16; msk <<= 1) {
            v0 += __shfl_xor(v0, msk);
            v1 += __shfl_xor(v1, msk);
            v2 += __shfl_xor(v2, msk);
            v3 += __shfl_xor(v3, msk);
        }
        oacc0[e] = v0; oacc1[e] = v1; oacc2[e] = v2; oacc3[e] = v3;
    }
    if (m == 0) {
        float* op = obuf + wave * 64 + qd4 * 8;
        *(fvec4*)(op)      = oacc0;
        *(fvec4*)(op + 4)  = oacc1;
        *(fvec4*)(op + 32) = oacc2;
        *(fvec4*)(op + 36) = oacc3;
    }
    __syncthreads();
    if (t < 64)
        out[(size_t)b * DIM + t] = obuf[t] + obuf[64 + t];
}

extern "C" void kernel_launch(void* const* d_in, const int* in_sizes, int n_in,
                              void* d_out, int out_size, void* d_ws, size_t ws_size,
                              hipStream_t stream) {
    const float* q      = (const float*)d_in[0];
    const float* key    = (const float*)d_in[1];
    const int*   seqlen = (const int*)d_in[2];
    const float* W1     = (const float*)d_in[3];
    const float* alpha1 = (const float*)d_in[4];
    const float* mean1  = (const float*)d_in[5];
    const float* var1   = (const float*)d_in[6];
    const float* W2     = (const float*)d_in[7];
    const float* alpha2 = (const float*)d_in[8];
    const float* mean2  = (const float*)d_in[9];
    const float* var2   = (const float*)d_in[10];
    const float* W3     = (const float*)d_in[11];
    float* out          = (float*)d_out;

    din_attn_kernel<<<NB, 128, 0, stream>>>(q, key, seqlen, W1,
                                            alpha1, mean1, var1,
                                            W2, alpha2, mean2, var2,
                                            W3, out);
}